// Round 18
// baseline (127.988 us; speedup 1.0000x reference)
//
#include <hip/hip_runtime.h>
#include <hip/hip_bf16.h>
#include <math.h>

#define B_     8
#define C_     256
#define HW_    1024
#define NTOT   (B_*C_*HW_)     // 2097152
#define HEADS_ 8
#define DK_    32
#define SCALE_ 0.17677669529663687f  // 32^-0.5

// workspace layout (float offsets)
#define F_STATS 0
#define F_PART  16
#define F_YK2   8192
#define F_YV2   (F_YK2 + NTOT)
#define F_XB    (F_YV2 + NTOT)
#define F_WT    (F_XB + NTOT/2)           // conv weights (bf16): 589824 floats
#define F_QB    (F_WT + 589824)
#define F_KB    (F_QB + NTOT/2)
#define F_VT    (F_KB + NTOT/2)
#define F_WT4   (F_VT + NTOT/2)           // proj weights (bf16), disjoint from F_WT
#define F_BETA0 (F_WT4 + 131072)

typedef float f32x4 __attribute__((ext_vector_type(4)));
typedef short short8 __attribute__((ext_vector_type(8)));

__device__ __forceinline__ short bf16s(float f) {
    __hip_bfloat16 h = __float2bfloat16(f);
    return *(short*)&h;
}
__device__ __forceinline__ unsigned pack_bf16(float a, float b) {
    unsigned ua = (unsigned short)bf16s(a);
    unsigned ub = (unsigned short)bf16s(b);
    return ua | (ub << 16);
}
__device__ __forceinline__ void gload_lds16(const short* g, short* l) {
    __builtin_amdgcn_global_load_lds(
        (const __attribute__((address_space(1))) unsigned*)g,
        (__attribute__((address_space(3))) unsigned*)l, 16, 0, 0);
}

// ---------------- merged prep: x->xb+LN partials | conv w | proj w ----------
__global__ void k_prep_all(const float* __restrict__ x,
                           const float* __restrict__ wk, const float* __restrict__ wv,
                           const float* __restrict__ Wq, const float* __restrict__ Wk,
                           const float* __restrict__ Wv, const float* __restrict__ Wo,
                           short* __restrict__ xb, float* __restrict__ part,
                           short* __restrict__ wt, short* __restrict__ wt4) {
    __shared__ short t[32 * 258];
    __shared__ float ls[4], ls2[4];
    int bid = blockIdx.x;
    int tid = threadIdx.x;
    if (bid < 256) {
        int b = bid >> 5, p0 = (bid & 31) << 5;
        float s = 0.f, s2 = 0.f;
        for (int i = tid; i < 256 * 32; i += 256) {
            int ci = i >> 5, p = i & 31;
            float v = x[(b * C_ + ci) * HW_ + p0 + p];
            s += v; s2 += v * v;
            t[p * 258 + ci] = bf16s(v);
        }
        for (int o = 32; o; o >>= 1) { s += __shfl_down(s, o); s2 += __shfl_down(s2, o); }
        int wid = tid >> 6, lane = tid & 63;
        if (lane == 0) { ls[wid] = s; ls2[wid] = s2; }
        __syncthreads();
        if (tid == 0) {
            float a = 0.f, bb = 0.f;
            for (int i = 0; i < 4; i++) { a += ls[i]; bb += ls2[i]; }
            part[bid * 2] = a; part[bid * 2 + 1] = bb;
        }
        for (int i = tid; i < 32 * 256; i += 256) {
            int p = i >> 8, ci = i & 255;
            xb[(b * HW_ + p0 + p) * C_ + ci] = t[p * 258 + ci];
        }
    } else if (bid < 1408) {
        int idx = (bid - 256) * 256 + tid;
        int ci0 = (idx << 2) & 255;
        int rest = idx >> 6;
        int n = rest & 511, tap = rest >> 9;
        const float* src = (n < 256) ? (wk + (n * C_) * 9) : (wv + ((n - 256) * C_) * 9);
        short4 o;
        short* op = (short*)&o;
        for (int u = 0; u < 4; u++)
            op[u] = bf16s(src[(ci0 + u) * 9 + tap]);
        *(short4*)&wt[((tap * 512 + n) * C_) + ci0] = o;
    } else {
        int b2 = bid - 1408;
        int mi = b2 >> 4, tl = b2 & 15;
        int c0 = (tl >> 2) * 64, e0 = (tl & 3) * 64;
        const float* W = mi == 0 ? Wq : mi == 1 ? Wk : mi == 2 ? Wv : Wo;
        for (int i = tid; i < 4096; i += 256) {
            int cl = i >> 6, el = i & 63;
            t[cl * 66 + el] = bf16s(W[(c0 + cl) * 256 + e0 + el]);
        }
        __syncthreads();
        for (int i = tid; i < 4096; i += 256) {
            int el = i >> 6, cl = i & 63;
            wt4[mi * 65536 + (e0 + el) * 256 + c0 + cl] = t[cl * 66 + el];
        }
    }
}

// ---------------- stats + beta0 (1 block, 1024 thr) -------------------------
__global__ void k_stats_beta(const float* __restrict__ part,
                             const float* __restrict__ Wq, const float* __restrict__ bq,
                             float* __restrict__ stats, float* __restrict__ beta0) {
    __shared__ float ls[256], ls2[256], ps[1024], st2[2];
    int tid = threadIdx.x;
    if (tid < 256) { ls[tid] = part[2 * tid]; ls2[tid] = part[2 * tid + 1]; }
    __syncthreads();
    for (int off = 128; off; off >>= 1) {
        if (tid < off) { ls[tid] += ls[tid + off]; ls2[tid] += ls2[tid + off]; }
        __syncthreads();
    }
    if (tid == 0) {
        float m = ls[0] / (float)NTOT;
        float var = ls2[0] / (float)NTOT - m * m;
        float r = rsqrtf(var + 1e-5f);
        stats[0] = m; stats[1] = r;
        st2[0] = m; st2[1] = r;
    }
    int e = tid & 255, pp = tid >> 8;
    float s = 0.f;
    for (int c = pp * 64; c < pp * 64 + 64; c++) s += Wq[c * 256 + e];
    ps[tid] = s;
    __syncthreads();
    if (tid < 256) {
        float cs = ps[tid] + ps[tid + 256] + ps[tid + 512] + ps[tid + 768];
        beta0[tid] = (bq[tid] - st2[0] * st2[1] * cs) * SCALE_;
    }
}

// ---------------- conv via MFMA implicit GEMM, high-occupancy retile --------
// grid 1024 = b(8) x pt(8: 128 px) x nt(16: 32 cols), nt in LOW bits
// block 512 = 8 waves; wave w: 16 px (w*16..) x 32 co; 31.5 KB LDS -> 4 blk/CU
__device__ __forceinline__ int a_off(int slot, int chunk) {
    int c = chunk ^ (slot & 3);
    int s = slot ^ ((slot >> 2) & 1);
    return s * 64 + c * 16;
}

__global__ __launch_bounds__(512, 8)
void k_conv_mfma(const short* __restrict__ xb, const short* __restrict__ wt,
                 const float* __restrict__ bk, const float* __restrict__ bv,
                 short* __restrict__ yk2b, short* __restrict__ yv2b) {
    __shared__ short a_sh[204 * 32];    // 6 rows x 34 cols x 32 ci (13 KB)
    __shared__ short b_sh[9 * 1024];    // [tap][128 slots of 8] (18 KB)
    int bid = blockIdx.x;
    int nt = bid & 15, pt = (bid >> 4) & 7, b = bid >> 7;
    int R0 = pt * 4;
    int tid = threadIdx.x;
    int w = tid >> 6, l = tid & 63;
    int col16 = l & 15, kq = l >> 4;

    // A staging: 816 items; thread does items tid, tid+512
    int offs[2], loffs[2];
    #pragma unroll
    for (int it = 0; it < 2; it++) {
        int i = tid + it * 512;
        if (i < 816) {
            int slot = i >> 2, chunk = i & 3;
            int ty = slot / 34, tx = slot - ty * 34;
            int Y = R0 - 1 + ty, X = tx - 1;
            offs[it] = ((unsigned)Y < 32u && (unsigned)X < 32u)
                       ? ((b * HW_ + Y * 32 + X) * C_ + chunk * 8) : -1;
            loffs[it] = a_off(slot, chunk);
        } else { offs[it] = -1; loffs[it] = -1; }
    }

    // B staging: 18 wave-instrs; wave w handles j = w, w+8, w+16
    int bgoff[3];
    int nbj = 0;
    #pragma unroll 1
    for (int j = w; j < 18; j += 8) {
        int S = j * 64 + l;
        int tap = S >> 7, s = S & 127;
        int colb = s >> 2, kqs = s & 3;
        int kq2 = kqs ^ ((colb >> 1) & 3);
        bgoff[nbj++] = (tap * 512 + nt * 32 + colb) * C_ + kq2 * 8;
    }

    f32x4 acc[2];
    acc[0] = (f32x4)0.f; acc[1] = (f32x4)0.f;

    int sr[2];
    #pragma unroll
    for (int nf = 0; nf < 2; nf++) {
        int colb = nf * 16 + col16;
        sr[nf] = (colb << 2) | (kq ^ ((colb >> 1) & 3));
    }

    {
        short8 sv[2];
        #pragma unroll
        for (int it = 0; it < 2; it++)
            sv[it] = (offs[it] >= 0) ? *(const short8*)(xb + offs[it]) : (short8)0;
        int jj = 0;
        #pragma unroll 1
        for (int j = w; j < 18; j += 8, jj++)
            gload_lds16(wt + bgoff[jj], b_sh + j * 512);
        #pragma unroll
        for (int it = 0; it < 2; it++)
            if (loffs[it] >= 0) *(short8*)((char*)a_sh + loffs[it]) = sv[it];
    }
    __syncthreads();

    int prow = w >> 1, pcol = (w & 1) * 16 + col16;   // px = w*16 + col16
    #pragma unroll 1
    for (int step = 0; step < 8; step++) {
        const char* ab = (const char*)a_sh;
        const char* bbp = (const char*)b_sh;
        #pragma unroll
        for (int tap = 0; tap < 9; tap++) {
            const int dyi = tap / 3, dxi = tap % 3;
            int slot = (prow + dyi) * 34 + pcol + dxi;
            short8 af = *(const short8*)(ab + a_off(slot, kq));
            short8 bf[2];
            #pragma unroll
            for (int nf = 0; nf < 2; nf++)
                bf[nf] = *(const short8*)(bbp + tap * 2048 + sr[nf] * 16);
            #pragma unroll
            for (int nf = 0; nf < 2; nf++)
                acc[nf] = __builtin_amdgcn_mfma_f32_16x16x32_bf16(af, bf[nf], acc[nf], 0, 0, 0);
        }
        if (step < 7) {
            int ci0n = step * 32 + 32;
            __syncthreads();
            short8 sv[2];
            #pragma unroll
            for (int it = 0; it < 2; it++)
                sv[it] = (offs[it] >= 0) ? *(const short8*)(xb + offs[it] + ci0n) : (short8)0;
            int jj = 0;
            #pragma unroll 1
            for (int j = w; j < 18; j += 8, jj++)
                gload_lds16(wt + bgoff[jj] + ci0n, b_sh + j * 512);
            #pragma unroll
            for (int it = 0; it < 2; it++)
                if (loffs[it] >= 0) *(short8*)((char*)a_sh + loffs[it]) = sv[it];
            __syncthreads();
        }
    }

    const bool isv = (nt >= 8);
    short* dst = isv ? yv2b : yk2b;
    const float* bias = isv ? bv : bk;
    int cbase = (nt & 7) * 32 + col16;
    #pragma unroll
    for (int nf = 0; nf < 2; nf++) {
        int co = cbase + nf * 16;
        float bi = bias[co];
        #pragma unroll
        for (int r = 0; r < 4; r++) {
            int pixel = pt * 128 + w * 16 + kq * 4 + r;
            dst[(b * HW_ + pixel) * C_ + co] = bf16s(acc[nf][r] + bi);
        }
    }
}

// ---------------- stage 3: projections via MFMA (unified bf16 inputs) -------
__global__ void k_proj_mfma(const short* __restrict__ xb,
                            const short* __restrict__ yk2b, const short* __restrict__ yv2b,
                            const short* __restrict__ wt4,
                            const float* __restrict__ bkp, const float* __restrict__ bvp,
                            const float* __restrict__ stats, const float* __restrict__ beta0,
                            short* __restrict__ qb, short* __restrict__ kb,
                            short* __restrict__ vt) {
    __shared__ char smem[17408];
    int pj = blockIdx.x, pt = blockIdx.y, b = blockIdx.z;
    int p0 = pt * 32;
    int tid = threadIdx.x, w = tid >> 6, l = tid & 63;
    int c16 = l & 15, kq = l >> 4;

    const short* src = pj == 0 ? xb : (pj == 1 ? yk2b : yv2b);
    #pragma unroll
    for (int it = 0; it < 4; it++) {
        int i = it * 256 + tid;
        int slab = i >> 7, rem = i & 127, slot = rem >> 2, chunk = rem & 3;
        short8 v = *(const short8*)(src + ((b * HW_ + p0 + slot) * C_ + slab * 32 + chunk * 8));
        *(short8*)(smem + slab * 2048 + a_off(slot, chunk)) = v;
    }
    __syncthreads();

    const short* wt_p = wt4 + pj * 65536;
    f32x4 acc[2][4];
    #pragma unroll
    for (int m = 0; m < 2; m++)
        #pragma unroll
        for (int n = 0; n < 4; n++) acc[m][n] = (f32x4)0.f;

    for (int s = 0; s < 8; s++) {
        short8 af[2], bf[4];
        #pragma unroll
        for (int mf = 0; mf < 2; mf++)
            af[mf] = *(const short8*)(smem + s * 2048 + a_off(mf * 16 + c16, kq));
        #pragma unroll
        for (int nf = 0; nf < 4; nf++)
            bf[nf] = *(const short8*)(wt_p + (w * 64 + nf * 16 + c16) * 256 + s * 32 + kq * 8);
        #pragma unroll
        for (int mf = 0; mf < 2; mf++)
            #pragma unroll
            for (int nf = 0; nf < 4; nf++)
                acc[mf][nf] = __builtin_amdgcn_mfma_f32_16x16x32_bf16(af[mf], bf[nf], acc[mf][nf], 0, 0, 0);
    }

    float alpha = (pj == 0) ? stats[1] * SCALE_ : 1.f;
    float beta[4];
    #pragma unroll
    for (int nf = 0; nf < 4; nf++) {
        int e = w * 64 + nf * 16 + c16;
        beta[nf] = (pj == 0) ? beta0[e] : (pj == 1 ? bkp[e] : bvp[e]);
    }
    __syncthreads();

    short* rp = (short*)smem + w * 2176;
    if (pj < 2) {
        #pragma unroll
        for (int mf = 0; mf < 2; mf++)
            #pragma unroll
            for (int nf = 0; nf < 4; nf++)
                #pragma unroll
                for (int rg = 0; rg < 4; rg++) {
                    int px = mf * 16 + kq * 4 + rg, el = nf * 16 + c16;
                    rp[px * 66 + el] = bf16s(alpha * acc[mf][nf][rg] + beta[nf]);
                }
        __syncthreads();
        short* dst = (pj == 0) ? qb : kb;
        #pragma unroll
        for (int j = 0; j < 4; j++) {
            int px = j * 8 + (l >> 3), el = (l & 7) * 8;
            short8 v = *(const short8*)(rp + px * 66 + el);
            int e = w * 64 + el, h = e >> 5, d = e & 31;
            *(short8*)(dst + ((b * 8 + h) * HW_ + p0 + px) * DK_ + d) = v;
        }
    } else {
        #pragma unroll
        for (int mf = 0; mf < 2; mf++)
            #pragma unroll
            for (int nf = 0; nf < 4; nf++)
                #pragma unroll
                for (int rg = 0; rg < 4; rg++) {
                    int px = mf * 16 + kq * 4 + rg, el = nf * 16 + c16;
                    rp[el * 34 + px] = bf16s(acc[mf][nf][rg] + beta[nf]);
                }
        __syncthreads();
        #pragma unroll
        for (int j = 0; j < 4; j++) {
            int el = j * 16 + (l >> 2), px = (l & 3) * 8;
            short8 v = *(const short8*)(rp + el * 34 + px);
            int e = w * 64 + el, h = e >> 5, d = e & 31;
            *(short8*)(vt + ((b * 8 + h) * DK_ + d) * HW_ + p0 + px) = v;
        }
    }
}

// ---------------- stage 4: attention (R14-proven: K gload_lds, in-reg P) ----
// grid: 1024 = qt(16) x b(8) x h(8), h in low bits; block 256 = 4 waves
__global__ __launch_bounds__(256, 4)
void k_attn(const short* __restrict__ qb, const short* __restrict__ kb,
            const short* __restrict__ vt, const float* __restrict__ Bb,
            short* __restrict__ ao) {
    __shared__ __align__(16) short Ks[128 * 32];     // [key][d] linear, 8 KB
    __shared__ __align__(16) short Vs[32 * 128];     // [dv][key] chunk-swizzled, 8 KB
    int bid = blockIdx.x;
    int h = bid & 7, b = (bid >> 3) & 7, qt = bid >> 6;
    int bh = b * HEADS_ + h;
    int tid = threadIdx.x, w = tid >> 6, l = tid & 63;
    int g = l >> 4, c16 = l & 15;

    int qrow = qt * 64 + w * 16 + c16;
    short8 qf = *(const short8*)(qb + (bh * HW_ + qrow) * DK_ + g * 8);
    const float* Brow = Bb + (h * HW_ + qrow) * HW_;

    float4 breg[8];
    #pragma unroll
    for (int mt = 0; mt < 8; mt++)
        breg[mt] = *(const float4*)(Brow + mt * 16 + g * 4);

    float m_run = -1e30f, l_run = 0.f;
    f32x4 ot[2];
    ot[0] = (f32x4)0.f; ot[1] = (f32x4)0.f;

    int vrow = tid >> 4, vch = tid & 15;
    int vrow2 = (tid + 256) >> 4, vch2 = (tid + 256) & 15;
    const short* kbase = kb + bh * HW_ * DK_;

    for (int kv0 = 0; kv0 < HW_; kv0 += 128) {
        __syncthreads();
        gload_lds16(kbase + kv0 * DK_ + (w * 2) * 512 + l * 8, Ks + (w * 2) * 512);
        gload_lds16(kbase + kv0 * DK_ + (w * 2 + 1) * 512 + l * 8, Ks + (w * 2 + 1) * 512);
        {
            short8 v0 = *(const short8*)(vt + (bh * DK_ + vrow) * HW_ + kv0 + vch * 8);
            short8 v1 = *(const short8*)(vt + (bh * DK_ + vrow2) * HW_ + kv0 + vch2 * 8);
            *(short8*)((char*)Vs + vrow * 256 + ((vch * 16) ^ ((vrow & 7) << 4))) = v0;
            *(short8*)((char*)Vs + vrow2 * 256 + ((vch2 * 16) ^ ((vrow2 & 7) << 4))) = v1;
        }
        __syncthreads();

        f32x4 st[8];
        __builtin_amdgcn_s_setprio(1);
        #pragma unroll
        for (int mt = 0; mt < 8; mt++) {
            f32x4 acc;
            acc[0] = breg[mt].x; acc[1] = breg[mt].y; acc[2] = breg[mt].z; acc[3] = breg[mt].w;
            short8 kf = *(const short8*)(Ks + (mt * 16 + c16) * DK_ + g * 8);
            st[mt] = __builtin_amdgcn_mfma_f32_16x16x32_bf16(kf, qf, acc, 0, 0, 0);
        }
        __builtin_amdgcn_s_setprio(0);
        if (kv0 + 128 < HW_) {
            #pragma unroll
            for (int mt = 0; mt < 8; mt++)
                breg[mt] = *(const float4*)(Brow + kv0 + 128 + mt * 16 + g * 4);
        }

        float pmax = st[0][0];
        #pragma unroll
        for (int mt = 0; mt < 8; mt++)
            #pragma unroll
            for (int rg = 0; rg < 4; rg++) pmax = fmaxf(pmax, st[mt][rg]);
        pmax = fmaxf(pmax, __shfl_xor(pmax, 16));
        pmax = fmaxf(pmax, __shfl_xor(pmax, 32));
        if (!__all(pmax <= m_run + 8.f)) {
            float mnew = fmaxf(m_run, pmax);
            float f = __expf(m_run - mnew);
            m_run = mnew;
            l_run *= f;
            int fv = __float_as_int(f);
            #pragma unroll
            for (int rg = 0; rg < 4; rg++) {
                float fr = __int_as_float(__builtin_amdgcn_ds_bpermute((g * 4 + rg) << 2, fv));
                ot[0][rg] *= fr;
                ot[1][rg] *= fr;
            }
        }
        float s = 0.f;
        #pragma unroll
        for (int mt = 0; mt < 8; mt++)
            #pragma unroll
            for (int rg = 0; rg < 4; rg++) {
                float e_ = __expf(st[mt][rg] - m_run);
                st[mt][rg] = e_;
                s += e_;
            }
        s += __shfl_xor(s, 16);
        s += __shfl_xor(s, 32);
        l_run += s;

        short8 pa[4];
        #pragma unroll
        for (int kt = 0; kt < 4; kt++) {
            unsigned u0 = pack_bf16(st[2 * kt][0], st[2 * kt][1]);
            unsigned u1 = pack_bf16(st[2 * kt][2], st[2 * kt][3]);
            unsigned u2 = pack_bf16(st[2 * kt + 1][0], st[2 * kt + 1][1]);
            unsigned u3 = pack_bf16(st[2 * kt + 1][2], st[2 * kt + 1][3]);
            unsigned* pu = (unsigned*)&pa[kt];
            pu[0] = u0; pu[1] = u1; pu[2] = u2; pu[3] = u3;
        }

        __builtin_amdgcn_s_setprio(1);
        #pragma unroll
        for (int kt = 0; kt < 4; kt++) {
            #pragma unroll
            for (int nt = 0; nt < 2; nt++) {
                int dv = c16 + 16 * nt;
                int X0 = kt * 64 + 8 * g;
                int X1 = X0 + 32;
                int a0 = dv * 256 + ((((X0 >> 4) ^ (dv & 7)) << 4) | (X0 & 15));
                int a1 = dv * 256 + ((((X1 >> 4) ^ (dv & 7)) << 4) | (X1 & 15));
                unsigned long long lo = *(const unsigned long long*)((char*)Vs + a0);
                unsigned long long hi = *(const unsigned long long*)((char*)Vs + a1);
                short8 vf;
                *(unsigned long long*)&vf = lo;
                *((unsigned long long*)&vf + 1) = hi;
                ot[nt] = __builtin_amdgcn_mfma_f32_16x16x32_bf16(pa[kt], vf, ot[nt], 0, 0, 0);
            }
        }
        __builtin_amdgcn_s_setprio(0);
    }

    float linv = 1.f / l_run;
    int lrv = __float_as_int(linv);
    #pragma unroll
    for (int rg = 0; rg < 4; rg++) {
        float li = __int_as_float(__builtin_amdgcn_ds_bpermute((g * 4 + rg) << 2, lrv));
        int qg = qt * 64 + w * 16 + g * 4 + rg;
        #pragma unroll
        for (int nt = 0; nt < 2; nt++)
            ao[(b * HW_ + qg) * C_ + h * DK_ + nt * 16 + c16] = bf16s(ot[nt][rg] * li);
    }
}

// ---------------- stage 5: output projection via MFMA + residual ------------
__global__ void k_out_mfma(const short* __restrict__ aob, const short* __restrict__ wot,
                           const float* __restrict__ bo, const float* __restrict__ x,
                           float* __restrict__ out) {
    __shared__ char smem[16384];
    int pt = blockIdx.x, b = blockIdx.y;
    int p0 = pt * 32;
    int tid = threadIdx.x, w = tid >> 6, l = tid & 63;
    int c16 = l & 15, kq = l >> 4;

    #pragma unroll
    for (int it = 0; it < 4; it++) {
        int i = it * 256 + tid;
        int slab = i >> 7, rem = i & 127, slot = rem >> 2, chunk = rem & 3;
        short8 v = *(const short8*)(aob + ((b * HW_ + p0 + slot) * C_ + slab * 32 + chunk * 8));
        *(short8*)(smem + slab * 2048 + a_off(slot, chunk)) = v;
    }
    __syncthreads();

    f32x4 acc[2][4];
    #pragma unroll
    for (int m = 0; m < 2; m++)
        #pragma unroll
        for (int n = 0; n < 4; n++) acc[m][n] = (f32x4)0.f;

    for (int s = 0; s < 8; s++) {
        short8 af[2], bf[4];
        #pragma unroll
        for (int mf = 0; mf < 2; mf++)
            af[mf] = *(const short8*)(smem + s * 2048 + a_off(mf * 16 + c16, kq));
        #pragma unroll
        for (int nf = 0; nf < 4; nf++)
            bf[nf] = *(const short8*)(wot + (w * 64 + nf * 16 + c16) * 256 + s * 32 + kq * 8);
        #pragma unroll
        for (int mf = 0; mf < 2; mf++)
            #pragma unroll
            for (int nf = 0; nf < 4; nf++)
                acc[mf][nf] = __builtin_amdgcn_mfma_f32_16x16x32_bf16(af[mf], bf[nf], acc[mf][nf], 0, 0, 0);
    }

    #pragma unroll
    for (int nf = 0; nf < 4; nf++) {
        int e = w * 64 + nf * 16 + c16;
        float bov = bo[e];
        #pragma unroll
        for (int mf = 0; mf < 2; mf++) {
            #pragma unroll
            for (int rg = 0; rg < 4; rg++) {
                int px = mf * 16 + kq * 4 + rg;
                int idx = b * (C_ * HW_) + (p0 + px) * 256 + e;
                out[idx] = acc[mf][nf][rg] + bov + x[idx];
            }
        }
    }
}

extern "C" void kernel_launch(void* const* d_in, const int* in_sizes, int n_in,
                              void* d_out, int out_size, void* d_ws, size_t ws_size,
                              hipStream_t stream) {
    const float* x   = (const float*)d_in[0];
    const float* Wq  = (const float*)d_in[1];
    const float* bq  = (const float*)d_in[2];
    const float* ckw = (const float*)d_in[3];
    const float* ckb = (const float*)d_in[4];
    const float* Wk  = (const float*)d_in[5];
    const float* bk  = (const float*)d_in[6];
    const float* cvw = (const float*)d_in[7];
    const float* cvb = (const float*)d_in[8];
    const float* Wv  = (const float*)d_in[9];
    const float* bv  = (const float*)d_in[10];
    const float* Wo  = (const float*)d_in[11];
    const float* bo  = (const float*)d_in[12];
    const float* Bb  = (const float*)d_in[13];
    float* ws  = (float*)d_ws;
    float* out = (float*)d_out;

    short* xb      = (short*)(ws + F_XB);
    short* wt      = (short*)(ws + F_WT);
    short* wt4     = (short*)(ws + F_WT4);
    float* beta0   = ws + F_BETA0;
    short* qb      = (short*)(ws + F_QB);
    short* kb      = (short*)(ws + F_KB);
    short* vt      = (short*)(ws + F_VT);
    short* yk2b    = (short*)(ws + F_YK2);
    short* yv2b    = (short*)(ws + F_YV2);
    short* aob     = (short*)(ws + F_YK2);   // alias: yk2b dead after proj
    short* wot     = wt4 + 3 * 65536;

    k_prep_all  <<<1472, 256, 0, stream>>>(x, ckw, cvw, Wq, Wk, Wv, Wo,
                                           xb, ws + F_PART, wt, wt4);
    k_stats_beta<<<1,   1024, 0, stream>>>(ws + F_PART, Wq, bq, ws + F_STATS, beta0);
    k_conv_mfma <<<1024, 512, 0, stream>>>(xb, wt, ckb, cvb, yk2b, yv2b);
    k_proj_mfma <<<dim3(3, 32, 8), 256, 0, stream>>>(xb, yk2b, yv2b,
                                                     wt4, bk, bv, ws + F_STATS, beta0,
                                                     qb, kb, vt);
    k_attn      <<<1024, 256, 0, stream>>>(qb, kb, vt, Bb, aob);
    k_out_mfma  <<<dim3(32, 8), 256, 0, stream>>>(aob, wot, bo, x, out);
}

// Round 19
// 124.275 us; speedup vs baseline: 1.0299x; 1.0299x over previous
//
#include <hip/hip_runtime.h>
#include <hip/hip_bf16.h>
#include <math.h>

#define B_     8
#define C_     256
#define HW_    1024
#define NTOT   (B_*C_*HW_)     // 2097152
#define HEADS_ 8
#define DK_    32
#define SCALE_ 0.17677669529663687f  // 32^-0.5

// workspace layout (float offsets)
#define F_STATS 0
#define F_PART  16
#define F_YK2   8192
#define F_YV2   (F_YK2 + NTOT)
#define F_XB    (F_YV2 + NTOT)
#define F_WT    (F_XB + NTOT/2)           // conv weights (bf16): 589824 floats
#define F_QB    (F_WT + 589824)
#define F_KB    (F_QB + NTOT/2)
#define F_VT    (F_KB + NTOT/2)
#define F_WT4   (F_VT + NTOT/2)           // proj weights (bf16), disjoint from F_WT
#define F_BETA0 (F_WT4 + 131072)

typedef float f32x4 __attribute__((ext_vector_type(4)));
typedef short short8 __attribute__((ext_vector_type(8)));

__device__ __forceinline__ short bf16s(float f) {
    __hip_bfloat16 h = __float2bfloat16(f);
    return *(short*)&h;
}
__device__ __forceinline__ unsigned pack_bf16(float a, float b) {
    unsigned ua = (unsigned short)bf16s(a);
    unsigned ub = (unsigned short)bf16s(b);
    return ua | (ub << 16);
}
__device__ __forceinline__ void gload_lds16(const short* g, short* l) {
    __builtin_amdgcn_global_load_lds(
        (const __attribute__((address_space(1))) unsigned*)g,
        (__attribute__((address_space(3))) unsigned*)l, 16, 0, 0);
}

// ---------------- merged prep: x->xb+LN partials | conv w | proj w ----------
__global__ void k_prep_all(const float* __restrict__ x,
                           const float* __restrict__ wk, const float* __restrict__ wv,
                           const float* __restrict__ Wq, const float* __restrict__ Wk,
                           const float* __restrict__ Wv, const float* __restrict__ Wo,
                           short* __restrict__ xb, float* __restrict__ part,
                           short* __restrict__ wt, short* __restrict__ wt4) {
    __shared__ short t[32 * 258];
    __shared__ float ls[4], ls2[4];
    int bid = blockIdx.x;
    int tid = threadIdx.x;
    if (bid < 256) {
        int b = bid >> 5, p0 = (bid & 31) << 5;
        float s = 0.f, s2 = 0.f;
        for (int i = tid; i < 256 * 32; i += 256) {
            int ci = i >> 5, p = i & 31;
            float v = x[(b * C_ + ci) * HW_ + p0 + p];
            s += v; s2 += v * v;
            t[p * 258 + ci] = bf16s(v);
        }
        for (int o = 32; o; o >>= 1) { s += __shfl_down(s, o); s2 += __shfl_down(s2, o); }
        int wid = tid >> 6, lane = tid & 63;
        if (lane == 0) { ls[wid] = s; ls2[wid] = s2; }
        __syncthreads();
        if (tid == 0) {
            float a = 0.f, bb = 0.f;
            for (int i = 0; i < 4; i++) { a += ls[i]; bb += ls2[i]; }
            part[bid * 2] = a; part[bid * 2 + 1] = bb;
        }
        for (int i = tid; i < 32 * 256; i += 256) {
            int p = i >> 8, ci = i & 255;
            xb[(b * HW_ + p0 + p) * C_ + ci] = t[p * 258 + ci];
        }
    } else if (bid < 1408) {
        int idx = (bid - 256) * 256 + tid;
        int ci0 = (idx << 2) & 255;
        int rest = idx >> 6;
        int n = rest & 511, tap = rest >> 9;
        const float* src = (n < 256) ? (wk + (n * C_) * 9) : (wv + ((n - 256) * C_) * 9);
        short4 o;
        short* op = (short*)&o;
        for (int u = 0; u < 4; u++)
            op[u] = bf16s(src[(ci0 + u) * 9 + tap]);
        *(short4*)&wt[((tap * 512 + n) * C_) + ci0] = o;
    } else {
        int b2 = bid - 1408;
        int mi = b2 >> 4, tl = b2 & 15;
        int c0 = (tl >> 2) * 64, e0 = (tl & 3) * 64;
        const float* W = mi == 0 ? Wq : mi == 1 ? Wk : mi == 2 ? Wv : Wo;
        for (int i = tid; i < 4096; i += 256) {
            int cl = i >> 6, el = i & 63;
            t[cl * 66 + el] = bf16s(W[(c0 + cl) * 256 + e0 + el]);
        }
        __syncthreads();
        for (int i = tid; i < 4096; i += 256) {
            int el = i >> 6, cl = i & 63;
            wt4[mi * 65536 + (e0 + el) * 256 + c0 + cl] = t[cl * 66 + el];
        }
    }
}

// ---------------- stats + beta0 (1 block, 1024 thr) -------------------------
__global__ void k_stats_beta(const float* __restrict__ part,
                             const float* __restrict__ Wq, const float* __restrict__ bq,
                             float* __restrict__ stats, float* __restrict__ beta0) {
    __shared__ float ls[256], ls2[256], ps[1024], st2[2];
    int tid = threadIdx.x;
    if (tid < 256) { ls[tid] = part[2 * tid]; ls2[tid] = part[2 * tid + 1]; }
    __syncthreads();
    for (int off = 128; off; off >>= 1) {
        if (tid < off) { ls[tid] += ls[tid + off]; ls2[tid] += ls2[tid + off]; }
        __syncthreads();
    }
    if (tid == 0) {
        float m = ls[0] / (float)NTOT;
        float var = ls2[0] / (float)NTOT - m * m;
        float r = rsqrtf(var + 1e-5f);
        stats[0] = m; stats[1] = r;
        st2[0] = m; st2[1] = r;
    }
    int e = tid & 255, pp = tid >> 8;
    float s = 0.f;
    for (int c = pp * 64; c < pp * 64 + 64; c++) s += Wq[c * 256 + e];
    ps[tid] = s;
    __syncthreads();
    if (tid < 256) {
        float cs = ps[tid] + ps[tid + 256] + ps[tid + 512] + ps[tid + 768];
        beta0[tid] = (bq[tid] - st2[0] * st2[1] * cs) * SCALE_;
    }
}

// ---------------- conv via MFMA implicit GEMM (R14-proven tiling) -----------
// grid 512 = b(8) x pt(8: 128 px) x nt(8: 64 cols), nt in LOW bits
// block 512 = 8 waves; wave: 32px x 32co; LDS 49 KB -> 2 blk/CU
__device__ __forceinline__ int a_off(int slot, int chunk) {
    int c = chunk ^ (slot & 3);
    int s = slot ^ ((slot >> 2) & 1);
    return s * 64 + c * 16;
}

__global__ __launch_bounds__(512, 4)
void k_conv_mfma(const short* __restrict__ xb, const short* __restrict__ wt,
                 const float* __restrict__ bk, const float* __restrict__ bv,
                 short* __restrict__ yk2b, short* __restrict__ yv2b) {
    __shared__ short a_sh[204 * 32];
    __shared__ short b_sh[9 * 2048];
    int bid = blockIdx.x;
    int nt = bid & 7, pt = (bid >> 3) & 7, b = bid >> 6;
    int R0 = pt * 4;
    int tid = threadIdx.x;
    int w = tid >> 6, l = tid & 63;
    int wm = w >> 1, wn = w & 1;
    int col16 = l & 15, kq = l >> 4;

    int offs[2], loffs[2];
    #pragma unroll
    for (int it = 0; it < 2; it++) {
        int i = tid + it * 512;
        if (i < 816) {
            int slot = i >> 2, chunk = i & 3;
            int ty = slot / 34, tx = slot - ty * 34;
            int Y = R0 - 1 + ty, X = tx - 1;
            offs[it] = ((unsigned)Y < 32u && (unsigned)X < 32u)
                       ? ((b * HW_ + Y * 32 + X) * C_ + chunk * 8) : -1;
            loffs[it] = a_off(slot, chunk);
        } else { offs[it] = -1; loffs[it] = -1; }
    }

    int bgoff[5];
    int nbj = 0;
    #pragma unroll 1
    for (int j = w; j < 36; j += 8) {
        int S = j * 64 + l;
        int tap = S >> 8, s = S & 255;
        int colb = s >> 2, kqs = s & 3;
        int kq2 = kqs ^ ((colb >> 1) & 3);
        bgoff[nbj++] = (tap * 512 + nt * 64 + colb) * C_ + kq2 * 8;
    }

    f32x4 acc[2][2];
    #pragma unroll
    for (int m = 0; m < 2; m++)
        #pragma unroll
        for (int n = 0; n < 2; n++) acc[m][n] = (f32x4)0.f;

    int sr[2];
    #pragma unroll
    for (int nf = 0; nf < 2; nf++) {
        int colb = wn * 32 + nf * 16 + col16;
        sr[nf] = (colb << 2) | (kq ^ ((colb >> 1) & 3));
    }

    {
        short8 sv[2];
        #pragma unroll
        for (int it = 0; it < 2; it++)
            sv[it] = (offs[it] >= 0) ? *(const short8*)(xb + offs[it]) : (short8)0;
        int jj = 0;
        #pragma unroll 1
        for (int j = w; j < 36; j += 8, jj++)
            gload_lds16(wt + bgoff[jj], b_sh + j * 512);
        #pragma unroll
        for (int it = 0; it < 2; it++)
            if (loffs[it] >= 0) *(short8*)((char*)a_sh + loffs[it]) = sv[it];
    }
    __syncthreads();

    #pragma unroll 1
    for (int step = 0; step < 8; step++) {
        const char* ab = (const char*)a_sh;
        const char* bbp = (const char*)b_sh;
        #pragma unroll
        for (int tap = 0; tap < 9; tap++) {
            const int dyi = tap / 3, dxi = tap % 3;
            short8 af[2], bf[2];
            #pragma unroll
            for (int mf = 0; mf < 2; mf++) {
                int slot = (wm + dyi) * 34 + mf * 16 + col16 + dxi;
                af[mf] = *(const short8*)(ab + a_off(slot, kq));
            }
            #pragma unroll
            for (int nf = 0; nf < 2; nf++)
                bf[nf] = *(const short8*)(bbp + tap * 4096 + sr[nf] * 16);
            #pragma unroll
            for (int mf = 0; mf < 2; mf++)
                #pragma unroll
                for (int nf = 0; nf < 2; nf++)
                    acc[mf][nf] = __builtin_amdgcn_mfma_f32_16x16x32_bf16(af[mf], bf[nf], acc[mf][nf], 0, 0, 0);
        }
        if (step < 7) {
            int ci0n = step * 32 + 32;
            __syncthreads();
            short8 sv[2];
            #pragma unroll
            for (int it = 0; it < 2; it++)
                sv[it] = (offs[it] >= 0) ? *(const short8*)(xb + offs[it] + ci0n) : (short8)0;
            int jj = 0;
            #pragma unroll 1
            for (int j = w; j < 36; j += 8, jj++)
                gload_lds16(wt + bgoff[jj] + ci0n, b_sh + j * 512);
            #pragma unroll
            for (int it = 0; it < 2; it++)
                if (loffs[it] >= 0) *(short8*)((char*)a_sh + loffs[it]) = sv[it];
            __syncthreads();
        }
    }

    const bool isv = (nt >= 4);
    short* dst = isv ? yv2b : yk2b;
    const float* bias = isv ? bv : bk;
    int cbase = (nt & 3) * 64 + wn * 32 + col16;
    #pragma unroll
    for (int nf = 0; nf < 2; nf++) {
        int co = cbase + nf * 16;
        float bi = bias[co];
        #pragma unroll
        for (int mf = 0; mf < 2; mf++) {
            #pragma unroll
            for (int r = 0; r < 4; r++) {
                int pixel = pt * 128 + wm * 32 + mf * 16 + kq * 4 + r;
                dst[(b * HW_ + pixel) * C_ + co] = bf16s(acc[mf][nf][r] + bi);
            }
        }
    }
}

// ---------------- stage 3: projections via MFMA (unified bf16 inputs) -------
__global__ void k_proj_mfma(const short* __restrict__ xb,
                            const short* __restrict__ yk2b, const short* __restrict__ yv2b,
                            const short* __restrict__ wt4,
                            const float* __restrict__ bkp, const float* __restrict__ bvp,
                            const float* __restrict__ stats, const float* __restrict__ beta0,
                            short* __restrict__ qb, short* __restrict__ kb,
                            short* __restrict__ vt) {
    __shared__ char smem[17408];
    int pj = blockIdx.x, pt = blockIdx.y, b = blockIdx.z;
    int p0 = pt * 32;
    int tid = threadIdx.x, w = tid >> 6, l = tid & 63;
    int c16 = l & 15, kq = l >> 4;

    const short* src = pj == 0 ? xb : (pj == 1 ? yk2b : yv2b);
    #pragma unroll
    for (int it = 0; it < 4; it++) {
        int i = it * 256 + tid;
        int slab = i >> 7, rem = i & 127, slot = rem >> 2, chunk = rem & 3;
        short8 v = *(const short8*)(src + ((b * HW_ + p0 + slot) * C_ + slab * 32 + chunk * 8));
        *(short8*)(smem + slab * 2048 + a_off(slot, chunk)) = v;
    }
    __syncthreads();

    const short* wt_p = wt4 + pj * 65536;
    f32x4 acc[2][4];
    #pragma unroll
    for (int m = 0; m < 2; m++)
        #pragma unroll
        for (int n = 0; n < 4; n++) acc[m][n] = (f32x4)0.f;

    for (int s = 0; s < 8; s++) {
        short8 af[2], bf[4];
        #pragma unroll
        for (int mf = 0; mf < 2; mf++)
            af[mf] = *(const short8*)(smem + s * 2048 + a_off(mf * 16 + c16, kq));
        #pragma unroll
        for (int nf = 0; nf < 4; nf++)
            bf[nf] = *(const short8*)(wt_p + (w * 64 + nf * 16 + c16) * 256 + s * 32 + kq * 8);
        #pragma unroll
        for (int mf = 0; mf < 2; mf++)
            #pragma unroll
            for (int nf = 0; nf < 4; nf++)
                acc[mf][nf] = __builtin_amdgcn_mfma_f32_16x16x32_bf16(af[mf], bf[nf], acc[mf][nf], 0, 0, 0);
    }

    float alpha = (pj == 0) ? stats[1] * SCALE_ : 1.f;
    float beta[4];
    #pragma unroll
    for (int nf = 0; nf < 4; nf++) {
        int e = w * 64 + nf * 16 + c16;
        beta[nf] = (pj == 0) ? beta0[e] : (pj == 1 ? bkp[e] : bvp[e]);
    }
    __syncthreads();

    short* rp = (short*)smem + w * 2176;
    if (pj < 2) {
        #pragma unroll
        for (int mf = 0; mf < 2; mf++)
            #pragma unroll
            for (int nf = 0; nf < 4; nf++)
                #pragma unroll
                for (int rg = 0; rg < 4; rg++) {
                    int px = mf * 16 + kq * 4 + rg, el = nf * 16 + c16;
                    rp[px * 66 + el] = bf16s(alpha * acc[mf][nf][rg] + beta[nf]);
                }
        __syncthreads();
        short* dst = (pj == 0) ? qb : kb;
        #pragma unroll
        for (int j = 0; j < 4; j++) {
            int px = j * 8 + (l >> 3), el = (l & 7) * 8;
            short8 v = *(const short8*)(rp + px * 66 + el);
            int e = w * 64 + el, h = e >> 5, d = e & 31;
            *(short8*)(dst + ((b * 8 + h) * HW_ + p0 + px) * DK_ + d) = v;
        }
    } else {
        #pragma unroll
        for (int mf = 0; mf < 2; mf++)
            #pragma unroll
            for (int nf = 0; nf < 4; nf++)
                #pragma unroll
                for (int rg = 0; rg < 4; rg++) {
                    int px = mf * 16 + kq * 4 + rg, el = nf * 16 + c16;
                    rp[el * 34 + px] = bf16s(acc[mf][nf][rg] + beta[nf]);
                }
        __syncthreads();
        #pragma unroll
        for (int j = 0; j < 4; j++) {
            int el = j * 16 + (l >> 2), px = (l & 3) * 8;
            short8 v = *(const short8*)(rp + el * 34 + px);
            int e = w * 64 + el, h = e >> 5, d = e & 31;
            *(short8*)(vt + ((b * 8 + h) * DK_ + d) * HW_ + p0 + px) = v;
        }
    }
}

// ---------------- stage 4: attention (R14-proven: K gload_lds, in-reg P) ----
// grid: 1024 = qt(16) x b(8) x h(8), h in low bits; block 256 = 4 waves
__global__ __launch_bounds__(256, 4)
void k_attn(const short* __restrict__ qb, const short* __restrict__ kb,
            const short* __restrict__ vt, const float* __restrict__ Bb,
            short* __restrict__ ao) {
    __shared__ __align__(16) short Ks[128 * 32];     // [key][d] linear, 8 KB
    __shared__ __align__(16) short Vs[32 * 128];     // [dv][key] chunk-swizzled, 8 KB
    int bid = blockIdx.x;
    int h = bid & 7, b = (bid >> 3) & 7, qt = bid >> 6;
    int bh = b * HEADS_ + h;
    int tid = threadIdx.x, w = tid >> 6, l = tid & 63;
    int g = l >> 4, c16 = l & 15;

    int qrow = qt * 64 + w * 16 + c16;
    short8 qf = *(const short8*)(qb + (bh * HW_ + qrow) * DK_ + g * 8);
    const float* Brow = Bb + (h * HW_ + qrow) * HW_;

    float4 breg[8];
    #pragma unroll
    for (int mt = 0; mt < 8; mt++)
        breg[mt] = *(const float4*)(Brow + mt * 16 + g * 4);

    float m_run = -1e30f, l_run = 0.f;
    f32x4 ot[2];
    ot[0] = (f32x4)0.f; ot[1] = (f32x4)0.f;

    int vrow = tid >> 4, vch = tid & 15;
    int vrow2 = (tid + 256) >> 4, vch2 = (tid + 256) & 15;
    const short* kbase = kb + bh * HW_ * DK_;

    for (int kv0 = 0; kv0 < HW_; kv0 += 128) {
        __syncthreads();
        gload_lds16(kbase + kv0 * DK_ + (w * 2) * 512 + l * 8, Ks + (w * 2) * 512);
        gload_lds16(kbase + kv0 * DK_ + (w * 2 + 1) * 512 + l * 8, Ks + (w * 2 + 1) * 512);
        {
            short8 v0 = *(const short8*)(vt + (bh * DK_ + vrow) * HW_ + kv0 + vch * 8);
            short8 v1 = *(const short8*)(vt + (bh * DK_ + vrow2) * HW_ + kv0 + vch2 * 8);
            *(short8*)((char*)Vs + vrow * 256 + ((vch * 16) ^ ((vrow & 7) << 4))) = v0;
            *(short8*)((char*)Vs + vrow2 * 256 + ((vch2 * 16) ^ ((vrow2 & 7) << 4))) = v1;
        }
        __syncthreads();

        f32x4 st[8];
        __builtin_amdgcn_s_setprio(1);
        #pragma unroll
        for (int mt = 0; mt < 8; mt++) {
            f32x4 acc;
            acc[0] = breg[mt].x; acc[1] = breg[mt].y; acc[2] = breg[mt].z; acc[3] = breg[mt].w;
            short8 kf = *(const short8*)(Ks + (mt * 16 + c16) * DK_ + g * 8);
            st[mt] = __builtin_amdgcn_mfma_f32_16x16x32_bf16(kf, qf, acc, 0, 0, 0);
        }
        __builtin_amdgcn_s_setprio(0);
        if (kv0 + 128 < HW_) {
            #pragma unroll
            for (int mt = 0; mt < 8; mt++)
                breg[mt] = *(const float4*)(Brow + kv0 + 128 + mt * 16 + g * 4);
        }

        float pmax = st[0][0];
        #pragma unroll
        for (int mt = 0; mt < 8; mt++)
            #pragma unroll
            for (int rg = 0; rg < 4; rg++) pmax = fmaxf(pmax, st[mt][rg]);
        pmax = fmaxf(pmax, __shfl_xor(pmax, 16));
        pmax = fmaxf(pmax, __shfl_xor(pmax, 32));
        if (!__all(pmax <= m_run + 8.f)) {
            float mnew = fmaxf(m_run, pmax);
            float f = __expf(m_run - mnew);
            m_run = mnew;
            l_run *= f;
            int fv = __float_as_int(f);
            #pragma unroll
            for (int rg = 0; rg < 4; rg++) {
                float fr = __int_as_float(__builtin_amdgcn_ds_bpermute((g * 4 + rg) << 2, fv));
                ot[0][rg] *= fr;
                ot[1][rg] *= fr;
            }
        }
        float s = 0.f;
        #pragma unroll
        for (int mt = 0; mt < 8; mt++)
            #pragma unroll
            for (int rg = 0; rg < 4; rg++) {
                float e_ = __expf(st[mt][rg] - m_run);
                st[mt][rg] = e_;
                s += e_;
            }
        s += __shfl_xor(s, 16);
        s += __shfl_xor(s, 32);
        l_run += s;

        short8 pa[4];
        #pragma unroll
        for (int kt = 0; kt < 4; kt++) {
            unsigned u0 = pack_bf16(st[2 * kt][0], st[2 * kt][1]);
            unsigned u1 = pack_bf16(st[2 * kt][2], st[2 * kt][3]);
            unsigned u2 = pack_bf16(st[2 * kt + 1][0], st[2 * kt + 1][1]);
            unsigned u3 = pack_bf16(st[2 * kt + 1][2], st[2 * kt + 1][3]);
            unsigned* pu = (unsigned*)&pa[kt];
            pu[0] = u0; pu[1] = u1; pu[2] = u2; pu[3] = u3;
        }

        __builtin_amdgcn_s_setprio(1);
        #pragma unroll
        for (int kt = 0; kt < 4; kt++) {
            #pragma unroll
            for (int nt = 0; nt < 2; nt++) {
                int dv = c16 + 16 * nt;
                int X0 = kt * 64 + 8 * g;
                int X1 = X0 + 32;
                int a0 = dv * 256 + ((((X0 >> 4) ^ (dv & 7)) << 4) | (X0 & 15));
                int a1 = dv * 256 + ((((X1 >> 4) ^ (dv & 7)) << 4) | (X1 & 15));
                unsigned long long lo = *(const unsigned long long*)((char*)Vs + a0);
                unsigned long long hi = *(const unsigned long long*)((char*)Vs + a1);
                short8 vf;
                *(unsigned long long*)&vf = lo;
                *((unsigned long long*)&vf + 1) = hi;
                ot[nt] = __builtin_amdgcn_mfma_f32_16x16x32_bf16(pa[kt], vf, ot[nt], 0, 0, 0);
            }
        }
        __builtin_amdgcn_s_setprio(0);
    }

    float linv = 1.f / l_run;
    int lrv = __float_as_int(linv);
    #pragma unroll
    for (int rg = 0; rg < 4; rg++) {
        float li = __int_as_float(__builtin_amdgcn_ds_bpermute((g * 4 + rg) << 2, lrv));
        int qg = qt * 64 + w * 16 + g * 4 + rg;
        #pragma unroll
        for (int nt = 0; nt < 2; nt++)
            ao[(b * HW_ + qg) * C_ + h * DK_ + nt * 16 + c16] = bf16s(ot[nt][rg] * li);
    }
}

// ---------------- stage 5: output projection via MFMA + residual ------------
__global__ void k_out_mfma(const short* __restrict__ aob, const short* __restrict__ wot,
                           const float* __restrict__ bo, const float* __restrict__ x,
                           float* __restrict__ out) {
    __shared__ char smem[16384];
    int pt = blockIdx.x, b = blockIdx.y;
    int p0 = pt * 32;
    int tid = threadIdx.x, w = tid >> 6, l = tid & 63;
    int c16 = l & 15, kq = l >> 4;

    #pragma unroll
    for (int it = 0; it < 4; it++) {
        int i = it * 256 + tid;
        int slab = i >> 7, rem = i & 127, slot = rem >> 2, chunk = rem & 3;
        short8 v = *(const short8*)(aob + ((b * HW_ + p0 + slot) * C_ + slab * 32 + chunk * 8));
        *(short8*)(smem + slab * 2048 + a_off(slot, chunk)) = v;
    }
    __syncthreads();

    f32x4 acc[2][4];
    #pragma unroll
    for (int m = 0; m < 2; m++)
        #pragma unroll
        for (int n = 0; n < 4; n++) acc[m][n] = (f32x4)0.f;

    for (int s = 0; s < 8; s++) {
        short8 af[2], bf[4];
        #pragma unroll
        for (int mf = 0; mf < 2; mf++)
            af[mf] = *(const short8*)(smem + s * 2048 + a_off(mf * 16 + c16, kq));
        #pragma unroll
        for (int nf = 0; nf < 4; nf++)
            bf[nf] = *(const short8*)(wot + (w * 64 + nf * 16 + c16) * 256 + s * 32 + kq * 8);
        #pragma unroll
        for (int mf = 0; mf < 2; mf++)
            #pragma unroll
            for (int nf = 0; nf < 4; nf++)
                acc[mf][nf] = __builtin_amdgcn_mfma_f32_16x16x32_bf16(af[mf], bf[nf], acc[mf][nf], 0, 0, 0);
    }

    #pragma unroll
    for (int nf = 0; nf < 4; nf++) {
        int e = w * 64 + nf * 16 + c16;
        float bov = bo[e];
        #pragma unroll
        for (int mf = 0; mf < 2; mf++) {
            #pragma unroll
            for (int rg = 0; rg < 4; rg++) {
                int px = mf * 16 + kq * 4 + rg;
                int idx = b * (C_ * HW_) + (p0 + px) * 256 + e;
                out[idx] = acc[mf][nf][rg] + bov + x[idx];
            }
        }
    }
}

extern "C" void kernel_launch(void* const* d_in, const int* in_sizes, int n_in,
                              void* d_out, int out_size, void* d_ws, size_t ws_size,
                              hipStream_t stream) {
    const float* x   = (const float*)d_in[0];
    const float* Wq  = (const float*)d_in[1];
    const float* bq  = (const float*)d_in[2];
    const float* ckw = (const float*)d_in[3];
    const float* ckb = (const float*)d_in[4];
    const float* Wk  = (const float*)d_in[5];
    const float* bk  = (const float*)d_in[6];
    const float* cvw = (const float*)d_in[7];
    const float* cvb = (const float*)d_in[8];
    const float* Wv  = (const float*)d_in[9];
    const float* bv  = (const float*)d_in[10];
    const float* Wo  = (const float*)d_in[11];
    const float* bo  = (const float*)d_in[12];
    const float* Bb  = (const float*)d_in[13];
    float* ws  = (float*)d_ws;
    float* out = (float*)d_out;

    short* xb      = (short*)(ws + F_XB);
    short* wt      = (short*)(ws + F_WT);
    short* wt4     = (short*)(ws + F_WT4);
    float* beta0   = ws + F_BETA0;
    short* qb      = (short*)(ws + F_QB);
    short* kb      = (short*)(ws + F_KB);
    short* vt      = (short*)(ws + F_VT);
    short* yk2b    = (short*)(ws + F_YK2);
    short* yv2b    = (short*)(ws + F_YV2);
    short* aob     = (short*)(ws + F_YK2);   // alias: yk2b dead after proj
    short* wot     = wt4 + 3 * 65536;

    k_prep_all  <<<1472, 256, 0, stream>>>(x, ckw, cvw, Wq, Wk, Wv, Wo,
                                           xb, ws + F_PART, wt, wt4);
    k_stats_beta<<<1,   1024, 0, stream>>>(ws + F_PART, Wq, bq, ws + F_STATS, beta0);
    k_conv_mfma <<<512,  512, 0, stream>>>(xb, wt, ckb, cvb, yk2b, yv2b);
    k_proj_mfma <<<dim3(3, 32, 8), 256, 0, stream>>>(xb, yk2b, yv2b,
                                                     wt4, bk, bv, ws + F_STATS, beta0,
                                                     qb, kb, vt);
    k_attn      <<<1024, 256, 0, stream>>>(qb, kb, vt, Bb, aob);
    k_out_mfma  <<<dim3(32, 8), 256, 0, stream>>>(aob, wot, bo, x, out);
}

// Round 20
// 123.963 us; speedup vs baseline: 1.0325x; 1.0025x over previous
//
#include <hip/hip_runtime.h>
#include <hip/hip_bf16.h>
#include <math.h>

#define B_     8
#define C_     256
#define HW_    1024
#define NTOT   (B_*C_*HW_)     // 2097152
#define HEADS_ 8
#define DK_    32
#define SCALE_ 0.17677669529663687f  // 32^-0.5

// workspace layout (float offsets)
#define F_STATS 0
#define F_PART  16
#define F_YK2   8192
#define F_YV2   (F_YK2 + NTOT)
#define F_XB    (F_YV2 + NTOT)
#define F_WT    (F_XB + NTOT/2)           // conv weights (bf16): 589824 floats
#define F_QB    (F_WT + 589824)
#define F_KB    (F_QB + NTOT/2)
#define F_VT    (F_KB + NTOT/2)
#define F_WT4   (F_VT + NTOT/2)           // proj weights (bf16), disjoint from F_WT
#define F_BETA0 (F_WT4 + 131072)

typedef float f32x4 __attribute__((ext_vector_type(4)));
typedef short short8 __attribute__((ext_vector_type(8)));

__device__ __forceinline__ short bf16s(float f) {
    __hip_bfloat16 h = __float2bfloat16(f);
    return *(short*)&h;
}
__device__ __forceinline__ unsigned pack_bf16(float a, float b) {
    unsigned ua = (unsigned short)bf16s(a);
    unsigned ub = (unsigned short)bf16s(b);
    return ua | (ub << 16);
}
__device__ __forceinline__ void gload_lds16(const short* g, short* l) {
    __builtin_amdgcn_global_load_lds(
        (const __attribute__((address_space(1))) unsigned*)g,
        (__attribute__((address_space(3))) unsigned*)l, 16, 0, 0);
}

// ---------------- merged prep: x->xb+LN partials | conv w (LDS transpose) | proj w
// grid 448 = [0,256) prep_x | [256,384) prep_w | [384,448) prep_pw
__global__ void k_prep_all(const float* __restrict__ x,
                           const float* __restrict__ wk, const float* __restrict__ wv,
                           const float* __restrict__ Wq, const float* __restrict__ Wk,
                           const float* __restrict__ Wv, const float* __restrict__ Wo,
                           short* __restrict__ xb, float* __restrict__ part,
                           short* __restrict__ wt, short* __restrict__ wt4) {
    __shared__ __align__(16) char sraw[36864];   // union: t (16.5KB) | fb (36.9KB)
    short* t = (short*)sraw;
    float* fb = (float*)sraw;
    __shared__ float ls[4], ls2[4];
    int bid = blockIdx.x;
    int tid = threadIdx.x;
    if (bid < 256) {
        int b = bid >> 5, p0 = (bid & 31) << 5;
        float s = 0.f, s2 = 0.f;
        for (int i = tid; i < 256 * 32; i += 256) {
            int ci = i >> 5, p = i & 31;
            float v = x[(b * C_ + ci) * HW_ + p0 + p];
            s += v; s2 += v * v;
            t[p * 258 + ci] = bf16s(v);
        }
        for (int o = 32; o; o >>= 1) { s += __shfl_down(s, o); s2 += __shfl_down(s2, o); }
        int wid = tid >> 6, lane = tid & 63;
        if (lane == 0) { ls[wid] = s; ls2[wid] = s2; }
        __syncthreads();
        if (tid == 0) {
            float a = 0.f, bb = 0.f;
            for (int i = 0; i < 4; i++) { a += ls[i]; bb += ls2[i]; }
            part[bid * 2] = a; part[bid * 2 + 1] = bb;
        }
        for (int i = tid; i < 32 * 256; i += 256) {
            int p = i >> 8, ci = i & 255;
            xb[(b * HW_ + p0 + p) * C_ + ci] = t[p * 258 + ci];
        }
    } else if (bid < 384) {
        // conv weights: coalesced load of 4 co's (9216 floats) -> LDS -> transposed bf16 store
        int b2 = bid - 256;
        int mat = b2 >> 6, co0 = (b2 & 63) * 4;
        const float* src = (mat == 0 ? wk : wv) + co0 * 2304;
        #pragma unroll
        for (int it = 0; it < 9; it++) {
            int i = it * 256 + tid;          // [0, 2304) float4 slots
            *(float4*)&fb[i * 4] = *(const float4*)&src[i * 4];
        }
        __syncthreads();
        #pragma unroll
        for (int it = 0; it < 9; it++) {
            int row = it * 4 + (tid >> 6);   // 0..35 = (cc, tap)
            int cc = row / 9, tap = row - cc * 9;
            int ci0 = (tid & 63) * 4;
            short4 o;
            short* op = (short*)&o;
            #pragma unroll
            for (int u = 0; u < 4; u++)
                op[u] = bf16s(fb[cc * 2304 + (ci0 + u) * 9 + tap]);
            *(short4*)&wt[(tap * 512 + mat * 256 + co0 + cc) * C_ + ci0] = o;
        }
    } else {
        int b2 = bid - 384;
        int mi = b2 >> 4, tl = b2 & 15;
        int c0 = (tl >> 2) * 64, e0 = (tl & 3) * 64;
        const float* W = mi == 0 ? Wq : mi == 1 ? Wk : mi == 2 ? Wv : Wo;
        for (int i = tid; i < 4096; i += 256) {
            int cl = i >> 6, el = i & 63;
            t[cl * 66 + el] = bf16s(W[(c0 + cl) * 256 + e0 + el]);
        }
        __syncthreads();
        for (int i = tid; i < 4096; i += 256) {
            int el = i >> 6, cl = i & 63;
            wt4[mi * 65536 + (e0 + el) * 256 + c0 + cl] = t[cl * 66 + el];
        }
    }
}

// ---------------- stats + beta0 (1 block, 1024 thr) -------------------------
__global__ void k_stats_beta(const float* __restrict__ part,
                             const float* __restrict__ Wq, const float* __restrict__ bq,
                             float* __restrict__ stats, float* __restrict__ beta0) {
    __shared__ float ls[256], ls2[256], ps[1024], st2[2];
    int tid = threadIdx.x;
    if (tid < 256) { ls[tid] = part[2 * tid]; ls2[tid] = part[2 * tid + 1]; }
    __syncthreads();
    for (int off = 128; off; off >>= 1) {
        if (tid < off) { ls[tid] += ls[tid + off]; ls2[tid] += ls2[tid + off]; }
        __syncthreads();
    }
    if (tid == 0) {
        float m = ls[0] / (float)NTOT;
        float var = ls2[0] / (float)NTOT - m * m;
        float r = rsqrtf(var + 1e-5f);
        stats[0] = m; stats[1] = r;
        st2[0] = m; st2[1] = r;
    }
    int e = tid & 255, pp = tid >> 8;
    float s = 0.f;
    for (int c = pp * 64; c < pp * 64 + 64; c++) s += Wq[c * 256 + e];
    ps[tid] = s;
    __syncthreads();
    if (tid < 256) {
        float cs = ps[tid] + ps[tid + 256] + ps[tid + 512] + ps[tid + 768];
        beta0[tid] = (bq[tid] - st2[0] * st2[1] * cs) * SCALE_;
    }
}

// ---------------- conv via MFMA implicit GEMM (R14-proven tiling) -----------
__device__ __forceinline__ int a_off(int slot, int chunk) {
    int c = chunk ^ (slot & 3);
    int s = slot ^ ((slot >> 2) & 1);
    return s * 64 + c * 16;
}

__global__ __launch_bounds__(512, 4)
void k_conv_mfma(const short* __restrict__ xb, const short* __restrict__ wt,
                 const float* __restrict__ bk, const float* __restrict__ bv,
                 short* __restrict__ yk2b, short* __restrict__ yv2b) {
    __shared__ short a_sh[204 * 32];
    __shared__ short b_sh[9 * 2048];
    int bid = blockIdx.x;
    int nt = bid & 7, pt = (bid >> 3) & 7, b = bid >> 6;
    int R0 = pt * 4;
    int tid = threadIdx.x;
    int w = tid >> 6, l = tid & 63;
    int wm = w >> 1, wn = w & 1;
    int col16 = l & 15, kq = l >> 4;

    int offs[2], loffs[2];
    #pragma unroll
    for (int it = 0; it < 2; it++) {
        int i = tid + it * 512;
        if (i < 816) {
            int slot = i >> 2, chunk = i & 3;
            int ty = slot / 34, tx = slot - ty * 34;
            int Y = R0 - 1 + ty, X = tx - 1;
            offs[it] = ((unsigned)Y < 32u && (unsigned)X < 32u)
                       ? ((b * HW_ + Y * 32 + X) * C_ + chunk * 8) : -1;
            loffs[it] = a_off(slot, chunk);
        } else { offs[it] = -1; loffs[it] = -1; }
    }

    int bgoff[5];
    int nbj = 0;
    #pragma unroll 1
    for (int j = w; j < 36; j += 8) {
        int S = j * 64 + l;
        int tap = S >> 8, s = S & 255;
        int colb = s >> 2, kqs = s & 3;
        int kq2 = kqs ^ ((colb >> 1) & 3);
        bgoff[nbj++] = (tap * 512 + nt * 64 + colb) * C_ + kq2 * 8;
    }

    f32x4 acc[2][2];
    #pragma unroll
    for (int m = 0; m < 2; m++)
        #pragma unroll
        for (int n = 0; n < 2; n++) acc[m][n] = (f32x4)0.f;

    int sr[2];
    #pragma unroll
    for (int nf = 0; nf < 2; nf++) {
        int colb = wn * 32 + nf * 16 + col16;
        sr[nf] = (colb << 2) | (kq ^ ((colb >> 1) & 3));
    }

    {
        short8 sv[2];
        #pragma unroll
        for (int it = 0; it < 2; it++)
            sv[it] = (offs[it] >= 0) ? *(const short8*)(xb + offs[it]) : (short8)0;
        int jj = 0;
        #pragma unroll 1
        for (int j = w; j < 36; j += 8, jj++)
            gload_lds16(wt + bgoff[jj], b_sh + j * 512);
        #pragma unroll
        for (int it = 0; it < 2; it++)
            if (loffs[it] >= 0) *(short8*)((char*)a_sh + loffs[it]) = sv[it];
    }
    __syncthreads();

    #pragma unroll 1
    for (int step = 0; step < 8; step++) {
        const char* ab = (const char*)a_sh;
        const char* bbp = (const char*)b_sh;
        #pragma unroll
        for (int tap = 0; tap < 9; tap++) {
            const int dyi = tap / 3, dxi = tap % 3;
            short8 af[2], bf[2];
            #pragma unroll
            for (int mf = 0; mf < 2; mf++) {
                int slot = (wm + dyi) * 34 + mf * 16 + col16 + dxi;
                af[mf] = *(const short8*)(ab + a_off(slot, kq));
            }
            #pragma unroll
            for (int nf = 0; nf < 2; nf++)
                bf[nf] = *(const short8*)(bbp + tap * 4096 + sr[nf] * 16);
            #pragma unroll
            for (int mf = 0; mf < 2; mf++)
                #pragma unroll
                for (int nf = 0; nf < 2; nf++)
                    acc[mf][nf] = __builtin_amdgcn_mfma_f32_16x16x32_bf16(af[mf], bf[nf], acc[mf][nf], 0, 0, 0);
        }
        if (step < 7) {
            int ci0n = step * 32 + 32;
            __syncthreads();
            short8 sv[2];
            #pragma unroll
            for (int it = 0; it < 2; it++)
                sv[it] = (offs[it] >= 0) ? *(const short8*)(xb + offs[it] + ci0n) : (short8)0;
            int jj = 0;
            #pragma unroll 1
            for (int j = w; j < 36; j += 8, jj++)
                gload_lds16(wt + bgoff[jj] + ci0n, b_sh + j * 512);
            #pragma unroll
            for (int it = 0; it < 2; it++)
                if (loffs[it] >= 0) *(short8*)((char*)a_sh + loffs[it]) = sv[it];
            __syncthreads();
        }
    }

    const bool isv = (nt >= 4);
    short* dst = isv ? yv2b : yk2b;
    const float* bias = isv ? bv : bk;
    int cbase = (nt & 3) * 64 + wn * 32 + col16;
    #pragma unroll
    for (int nf = 0; nf < 2; nf++) {
        int co = cbase + nf * 16;
        float bi = bias[co];
        #pragma unroll
        for (int mf = 0; mf < 2; mf++) {
            #pragma unroll
            for (int r = 0; r < 4; r++) {
                int pixel = pt * 128 + wm * 32 + mf * 16 + kq * 4 + r;
                dst[(b * HW_ + pixel) * C_ + co] = bf16s(acc[mf][nf][r] + bi);
            }
        }
    }
}

// ---------------- stage 3: projections via MFMA (unified bf16 inputs) -------
__global__ void k_proj_mfma(const short* __restrict__ xb,
                            const short* __restrict__ yk2b, const short* __restrict__ yv2b,
                            const short* __restrict__ wt4,
                            const float* __restrict__ bkp, const float* __restrict__ bvp,
                            const float* __restrict__ stats, const float* __restrict__ beta0,
                            short* __restrict__ qb, short* __restrict__ kb,
                            short* __restrict__ vt) {
    __shared__ char smem[17408];
    int pj = blockIdx.x, pt = blockIdx.y, b = blockIdx.z;
    int p0 = pt * 32;
    int tid = threadIdx.x, w = tid >> 6, l = tid & 63;
    int c16 = l & 15, kq = l >> 4;

    const short* src = pj == 0 ? xb : (pj == 1 ? yk2b : yv2b);
    #pragma unroll
    for (int it = 0; it < 4; it++) {
        int i = it * 256 + tid;
        int slab = i >> 7, rem = i & 127, slot = rem >> 2, chunk = rem & 3;
        short8 v = *(const short8*)(src + ((b * HW_ + p0 + slot) * C_ + slab * 32 + chunk * 8));
        *(short8*)(smem + slab * 2048 + a_off(slot, chunk)) = v;
    }
    __syncthreads();

    const short* wt_p = wt4 + pj * 65536;
    f32x4 acc[2][4];
    #pragma unroll
    for (int m = 0; m < 2; m++)
        #pragma unroll
        for (int n = 0; n < 4; n++) acc[m][n] = (f32x4)0.f;

    for (int s = 0; s < 8; s++) {
        short8 af[2], bf[4];
        #pragma unroll
        for (int mf = 0; mf < 2; mf++)
            af[mf] = *(const short8*)(smem + s * 2048 + a_off(mf * 16 + c16, kq));
        #pragma unroll
        for (int nf = 0; nf < 4; nf++)
            bf[nf] = *(const short8*)(wt_p + (w * 64 + nf * 16 + c16) * 256 + s * 32 + kq * 8);
        #pragma unroll
        for (int mf = 0; mf < 2; mf++)
            #pragma unroll
            for (int nf = 0; nf < 4; nf++)
                acc[mf][nf] = __builtin_amdgcn_mfma_f32_16x16x32_bf16(af[mf], bf[nf], acc[mf][nf], 0, 0, 0);
    }

    float alpha = (pj == 0) ? stats[1] * SCALE_ : 1.f;
    float beta[4];
    #pragma unroll
    for (int nf = 0; nf < 4; nf++) {
        int e = w * 64 + nf * 16 + c16;
        beta[nf] = (pj == 0) ? beta0[e] : (pj == 1 ? bkp[e] : bvp[e]);
    }
    __syncthreads();

    short* rp = (short*)smem + w * 2176;
    if (pj < 2) {
        #pragma unroll
        for (int mf = 0; mf < 2; mf++)
            #pragma unroll
            for (int nf = 0; nf < 4; nf++)
                #pragma unroll
                for (int rg = 0; rg < 4; rg++) {
                    int px = mf * 16 + kq * 4 + rg, el = nf * 16 + c16;
                    rp[px * 66 + el] = bf16s(alpha * acc[mf][nf][rg] + beta[nf]);
                }
        __syncthreads();
        short* dst = (pj == 0) ? qb : kb;
        #pragma unroll
        for (int j = 0; j < 4; j++) {
            int px = j * 8 + (l >> 3), el = (l & 7) * 8;
            short8 v = *(const short8*)(rp + px * 66 + el);
            int e = w * 64 + el, h = e >> 5, d = e & 31;
            *(short8*)(dst + ((b * 8 + h) * HW_ + p0 + px) * DK_ + d) = v;
        }
    } else {
        #pragma unroll
        for (int mf = 0; mf < 2; mf++)
            #pragma unroll
            for (int nf = 0; nf < 4; nf++)
                #pragma unroll
                for (int rg = 0; rg < 4; rg++) {
                    int px = mf * 16 + kq * 4 + rg, el = nf * 16 + c16;
                    rp[el * 34 + px] = bf16s(acc[mf][nf][rg] + beta[nf]);
                }
        __syncthreads();
        #pragma unroll
        for (int j = 0; j < 4; j++) {
            int el = j * 16 + (l >> 2), px = (l & 3) * 8;
            short8 v = *(const short8*)(rp + el * 34 + px);
            int e = w * 64 + el, h = e >> 5, d = e & 31;
            *(short8*)(vt + ((b * 8 + h) * DK_ + d) * HW_ + p0 + px) = v;
        }
    }
}

// ---------------- stage 4: attention (R14-proven: K gload_lds, in-reg P) ----
__global__ __launch_bounds__(256, 4)
void k_attn(const short* __restrict__ qb, const short* __restrict__ kb,
            const short* __restrict__ vt, const float* __restrict__ Bb,
            short* __restrict__ ao) {
    __shared__ __align__(16) short Ks[128 * 32];
    __shared__ __align__(16) short Vs[32 * 128];
    int bid = blockIdx.x;
    int h = bid & 7, b = (bid >> 3) & 7, qt = bid >> 6;
    int bh = b * HEADS_ + h;
    int tid = threadIdx.x, w = tid >> 6, l = tid & 63;
    int g = l >> 4, c16 = l & 15;

    int qrow = qt * 64 + w * 16 + c16;
    short8 qf = *(const short8*)(qb + (bh * HW_ + qrow) * DK_ + g * 8);
    const float* Brow = Bb + (h * HW_ + qrow) * HW_;

    float4 breg[8];
    #pragma unroll
    for (int mt = 0; mt < 8; mt++)
        breg[mt] = *(const float4*)(Brow + mt * 16 + g * 4);

    float m_run = -1e30f, l_run = 0.f;
    f32x4 ot[2];
    ot[0] = (f32x4)0.f; ot[1] = (f32x4)0.f;

    int vrow = tid >> 4, vch = tid & 15;
    int vrow2 = (tid + 256) >> 4, vch2 = (tid + 256) & 15;
    const short* kbase = kb + bh * HW_ * DK_;

    for (int kv0 = 0; kv0 < HW_; kv0 += 128) {
        __syncthreads();
        gload_lds16(kbase + kv0 * DK_ + (w * 2) * 512 + l * 8, Ks + (w * 2) * 512);
        gload_lds16(kbase + kv0 * DK_ + (w * 2 + 1) * 512 + l * 8, Ks + (w * 2 + 1) * 512);
        {
            short8 v0 = *(const short8*)(vt + (bh * DK_ + vrow) * HW_ + kv0 + vch * 8);
            short8 v1 = *(const short8*)(vt + (bh * DK_ + vrow2) * HW_ + kv0 + vch2 * 8);
            *(short8*)((char*)Vs + vrow * 256 + ((vch * 16) ^ ((vrow & 7) << 4))) = v0;
            *(short8*)((char*)Vs + vrow2 * 256 + ((vch2 * 16) ^ ((vrow2 & 7) << 4))) = v1;
        }
        __syncthreads();

        f32x4 st[8];
        __builtin_amdgcn_s_setprio(1);
        #pragma unroll
        for (int mt = 0; mt < 8; mt++) {
            f32x4 acc;
            acc[0] = breg[mt].x; acc[1] = breg[mt].y; acc[2] = breg[mt].z; acc[3] = breg[mt].w;
            short8 kf = *(const short8*)(Ks + (mt * 16 + c16) * DK_ + g * 8);
            st[mt] = __builtin_amdgcn_mfma_f32_16x16x32_bf16(kf, qf, acc, 0, 0, 0);
        }
        __builtin_amdgcn_s_setprio(0);
        if (kv0 + 128 < HW_) {
            #pragma unroll
            for (int mt = 0; mt < 8; mt++)
                breg[mt] = *(const float4*)(Brow + kv0 + 128 + mt * 16 + g * 4);
        }

        float pmax = st[0][0];
        #pragma unroll
        for (int mt = 0; mt < 8; mt++)
            #pragma unroll
            for (int rg = 0; rg < 4; rg++) pmax = fmaxf(pmax, st[mt][rg]);
        pmax = fmaxf(pmax, __shfl_xor(pmax, 16));
        pmax = fmaxf(pmax, __shfl_xor(pmax, 32));
        if (!__all(pmax <= m_run + 8.f)) {
            float mnew = fmaxf(m_run, pmax);
            float f = __expf(m_run - mnew);
            m_run = mnew;
            l_run *= f;
            int fv = __float_as_int(f);
            #pragma unroll
            for (int rg = 0; rg < 4; rg++) {
                float fr = __int_as_float(__builtin_amdgcn_ds_bpermute((g * 4 + rg) << 2, fv));
                ot[0][rg] *= fr;
                ot[1][rg] *= fr;
            }
        }
        float s = 0.f;
        #pragma unroll
        for (int mt = 0; mt < 8; mt++)
            #pragma unroll
            for (int rg = 0; rg < 4; rg++) {
                float e_ = __expf(st[mt][rg] - m_run);
                st[mt][rg] = e_;
                s += e_;
            }
        s += __shfl_xor(s, 16);
        s += __shfl_xor(s, 32);
        l_run += s;

        short8 pa[4];
        #pragma unroll
        for (int kt = 0; kt < 4; kt++) {
            unsigned u0 = pack_bf16(st[2 * kt][0], st[2 * kt][1]);
            unsigned u1 = pack_bf16(st[2 * kt][2], st[2 * kt][3]);
            unsigned u2 = pack_bf16(st[2 * kt + 1][0], st[2 * kt + 1][1]);
            unsigned u3 = pack_bf16(st[2 * kt + 1][2], st[2 * kt + 1][3]);
            unsigned* pu = (unsigned*)&pa[kt];
            pu[0] = u0; pu[1] = u1; pu[2] = u2; pu[3] = u3;
        }

        __builtin_amdgcn_s_setprio(1);
        #pragma unroll
        for (int kt = 0; kt < 4; kt++) {
            #pragma unroll
            for (int nt = 0; nt < 2; nt++) {
                int dv = c16 + 16 * nt;
                int X0 = kt * 64 + 8 * g;
                int X1 = X0 + 32;
                int a0 = dv * 256 + ((((X0 >> 4) ^ (dv & 7)) << 4) | (X0 & 15));
                int a1 = dv * 256 + ((((X1 >> 4) ^ (dv & 7)) << 4) | (X1 & 15));
                unsigned long long lo = *(const unsigned long long*)((char*)Vs + a0);
                unsigned long long hi = *(const unsigned long long*)((char*)Vs + a1);
                short8 vf;
                *(unsigned long long*)&vf = lo;
                *((unsigned long long*)&vf + 1) = hi;
                ot[nt] = __builtin_amdgcn_mfma_f32_16x16x32_bf16(pa[kt], vf, ot[nt], 0, 0, 0);
            }
        }
        __builtin_amdgcn_s_setprio(0);
    }

    float linv = 1.f / l_run;
    int lrv = __float_as_int(linv);
    #pragma unroll
    for (int rg = 0; rg < 4; rg++) {
        float li = __int_as_float(__builtin_amdgcn_ds_bpermute((g * 4 + rg) << 2, lrv));
        int qg = qt * 64 + w * 16 + g * 4 + rg;
        #pragma unroll
        for (int nt = 0; nt < 2; nt++)
            ao[(b * HW_ + qg) * C_ + h * DK_ + nt * 16 + c16] = bf16s(ot[nt][rg] * li);
    }
}

// ---------------- stage 5: output projection via MFMA + residual ------------
__global__ void k_out_mfma(const short* __restrict__ aob, const short* __restrict__ wot,
                           const float* __restrict__ bo, const float* __restrict__ x,
                           float* __restrict__ out) {
    __shared__ char smem[16384];
    int pt = blockIdx.x, b = blockIdx.y;
    int p0 = pt * 32;
    int tid = threadIdx.x, w = tid >> 6, l = tid & 63;
    int c16 = l & 15, kq = l >> 4;

    #pragma unroll
    for (int it = 0; it < 4; it++) {
        int i = it * 256 + tid;
        int slab = i >> 7, rem = i & 127, slot = rem >> 2, chunk = rem & 3;
        short8 v = *(const short8*)(aob + ((b * HW_ + p0 + slot) * C_ + slab * 32 + chunk * 8));
        *(short8*)(smem + slab * 2048 + a_off(slot, chunk)) = v;
    }
    __syncthreads();

    f32x4 acc[2][4];
    #pragma unroll
    for (int m = 0; m < 2; m++)
        #pragma unroll
        for (int n = 0; n < 4; n++) acc[m][n] = (f32x4)0.f;

    for (int s = 0; s < 8; s++) {
        short8 af[2], bf[4];
        #pragma unroll
        for (int mf = 0; mf < 2; mf++)
            af[mf] = *(const short8*)(smem + s * 2048 + a_off(mf * 16 + c16, kq));
        #pragma unroll
        for (int nf = 0; nf < 4; nf++)
            bf[nf] = *(const short8*)(wot + (w * 64 + nf * 16 + c16) * 256 + s * 32 + kq * 8);
        #pragma unroll
        for (int mf = 0; mf < 2; mf++)
            #pragma unroll
            for (int nf = 0; nf < 4; nf++)
                acc[mf][nf] = __builtin_amdgcn_mfma_f32_16x16x32_bf16(af[mf], bf[nf], acc[mf][nf], 0, 0, 0);
    }

    #pragma unroll
    for (int nf = 0; nf < 4; nf++) {
        int e = w * 64 + nf * 16 + c16;
        float bov = bo[e];
        #pragma unroll
        for (int mf = 0; mf < 2; mf++) {
            #pragma unroll
            for (int rg = 0; rg < 4; rg++) {
                int px = mf * 16 + kq * 4 + rg;
                int idx = b * (C_ * HW_) + (p0 + px) * 256 + e;
                out[idx] = acc[mf][nf][rg] + bov + x[idx];
            }
        }
    }
}

extern "C" void kernel_launch(void* const* d_in, const int* in_sizes, int n_in,
                              void* d_out, int out_size, void* d_ws, size_t ws_size,
                              hipStream_t stream) {
    const float* x   = (const float*)d_in[0];
    const float* Wq  = (const float*)d_in[1];
    const float* bq  = (const float*)d_in[2];
    const float* ckw = (const float*)d_in[3];
    const float* ckb = (const float*)d_in[4];
    const float* Wk  = (const float*)d_in[5];
    const float* bk  = (const float*)d_in[6];
    const float* cvw = (const float*)d_in[7];
    const float* cvb = (const float*)d_in[8];
    const float* Wv  = (const float*)d_in[9];
    const float* bv  = (const float*)d_in[10];
    const float* Wo  = (const float*)d_in[11];
    const float* bo  = (const float*)d_in[12];
    const float* Bb  = (const float*)d_in[13];
    float* ws  = (float*)d_ws;
    float* out = (float*)d_out;

    short* xb      = (short*)(ws + F_XB);
    short* wt      = (short*)(ws + F_WT);
    short* wt4     = (short*)(ws + F_WT4);
    float* beta0   = ws + F_BETA0;
    short* qb      = (short*)(ws + F_QB);
    short* kb      = (short*)(ws + F_KB);
    short* vt      = (short*)(ws + F_VT);
    short* yk2b    = (short*)(ws + F_YK2);
    short* yv2b    = (short*)(ws + F_YV2);
    short* aob     = (short*)(ws + F_YK2);   // alias: yk2b dead after proj
    short* wot     = wt4 + 3 * 65536;

    k_prep_all  <<<448,  256, 0, stream>>>(x, ckw, cvw, Wq, Wk, Wv, Wo,
                                           xb, ws + F_PART, wt, wt4);
    k_stats_beta<<<1,   1024, 0, stream>>>(ws + F_PART, Wq, bq, ws + F_STATS, beta0);
    k_conv_mfma <<<512,  512, 0, stream>>>(xb, wt, ckb, cvb, yk2b, yv2b);
    k_proj_mfma <<<dim3(3, 32, 8), 256, 0, stream>>>(xb, yk2b, yv2b,
                                                     wt4, bk, bv, ws + F_STATS, beta0,
                                                     qb, kb, vt);
    k_attn      <<<1024, 256, 0, stream>>>(qb, kb, vt, Bb, aob);
    k_out_mfma  <<<dim3(32, 8), 256, 0, stream>>>(aob, wot, bo, x, out);
}